// Round 3
// baseline (249.383 us; speedup 1.0000x reference)
//
#include <hip/hip_runtime.h>
#include <hip/hip_bf16.h>
#include <stdint.h>
#include <stddef.h>

// ---------------------------------------------------------------------------
// InteractionPredictionHead: edge MLP over a graph.
// Rewrite: feats@W1 = P[src] + Q[dst] + attr@W1c + b1 (P,Q per-node: 50k not 300k).
// R2 changes:
//  - fused/gemm1: 32 edges(nodes)/wave (acc2 halved: unified VGPR+AGPR file was
//    capping occupancy at 2 waves/SIMD).
//  - fused: NO weight LDS staging (W2t/W3t/W4t read from L2-hot ws image);
//    zero __syncthreads in main body (hslot is per-wave). Only W1c (3KB) in LDS.
//  - 2-deep p/q (and emb) prefetch with NAMED buffers (static indexing only).
//  - v_cvt_pk_bf16_f32 (1 instr / 2 elems) replaces 3-op manual RNE; h1 built
//    with f32x2 packed math.
// ---------------------------------------------------------------------------

#define NN 50000
#define NE 300000

using bf16x8 = __attribute__((ext_vector_type(8))) short;
using f32x16 = __attribute__((ext_vector_type(16))) float;
using f32x4  = __attribute__((ext_vector_type(4))) float;
using f32x2  = __attribute__((ext_vector_type(2))) float;
using u32x4  = __attribute__((ext_vector_type(4))) unsigned int;
using u32x2  = __attribute__((ext_vector_type(2))) unsigned int;

// ---- ws layout (bytes, 16B aligned) ----
#define OFF_PQ   0ULL
#define SZ_PQ    (50000ULL*512ULL*2ULL)          // PQ bf16 [n][512]
#define OFF_W1   (OFF_PQ + SZ_PQ)                // W1ab^T bf16 [512 out][256 k]
#define SZ_W1    (512ULL*256ULL*2ULL)
#define OFF_W1C  (OFF_W1 + SZ_W1)                // W1c f32 [3][256]
#define SZ_W1C   (3ULL*256ULL*4ULL)
#define OFF_W2   (OFF_W1C + SZ_W1C)              // W2^T bf16 [128 out][256 k]
#define SZ_W2    (128ULL*256ULL*2ULL)
#define OFF_W3   (OFF_W2 + SZ_W2)                // W3^T bf16 [64 out][128 k]
#define SZ_W3    (64ULL*128ULL*2ULL)
#define OFF_W4   (OFF_W3 + SZ_W3)                // W4^T bf16 [32 out(pad)][64 k]
#define SZ_W4    (32ULL*64ULL*2ULL)
#define OFF_FLAG (OFF_W4 + SZ_W4)
#define WS_NEED  (OFF_FLAG + 16ULL)

__device__ __forceinline__ unsigned short f2bf(float x){
  unsigned u = __float_as_uint(x);
  unsigned r = 0x7FFFu + ((u >> 16) & 1u);
  return (unsigned short)((u + r) >> 16);
}
__device__ __forceinline__ unsigned cvtpk(float lo, float hi){
  unsigned r;
  asm("v_cvt_pk_bf16_f32 %0, %1, %2" : "=v"(r) : "v"(lo), "v"(hi));
  return r;
}
__device__ __forceinline__ f32x2 unpk(unsigned w){
  f32x2 r;
  r[0] = __uint_as_float(w << 16);
  r[1] = __uint_as_float(w & 0xFFFF0000u);
  return r;
}
__device__ __forceinline__ f32x16 mfma32(bf16x8 a, bf16x8 b, f32x16 c){
  return __builtin_amdgcn_mfma_f32_32x32x16_bf16(a, b, c, 0, 0, 0);
}
__device__ __forceinline__ f32x16 zero16(){
  f32x16 v;
#pragma unroll
  for (int i = 0; i < 16; ++i) v[i] = 0.f;
  return v;
}

// ---------------------------------------------------------------------------
// prep_pack: weight bf16 images + int64-detection flag.
// threads = 131072 (W1t) + 32768 (W2t) + 8192 (W3t) + 2048 (W4t) = 174080
// ---------------------------------------------------------------------------
__global__ void prep_pack(const float* __restrict__ W1, const float* __restrict__ W2,
                          const float* __restrict__ W3, const float* __restrict__ W4,
                          const int* __restrict__ ei32, char* __restrict__ ws)
{
  int i = blockIdx.x * 256 + threadIdx.x;
  unsigned short* w1i = (unsigned short*)(ws + OFF_W1);
  unsigned short* w2i = (unsigned short*)(ws + OFF_W2);
  unsigned short* w3i = (unsigned short*)(ws + OFF_W3);
  unsigned short* w4i = (unsigned short*)(ws + OFF_W4);

  if (i < 131072){
    int r = i >> 8, k = i & 255;
    float v = (r < 256) ? W1[(size_t)k*256 + r] : W1[(size_t)(256 + k)*256 + (r - 256)];
    w1i[i] = f2bf(v);
  } else if (i < 131072 + 32768){
    int i2 = i - 131072;
    int r = i2 >> 8, k = i2 & 255;
    w2i[i2] = f2bf(W2[(size_t)k*128 + r]);
  } else if (i < 131072 + 32768 + 8192){
    int i3 = i - 131072 - 32768;
    int r = i3 >> 7, k = i3 & 127;
    w3i[i3] = f2bf(W3[(size_t)k*64 + r]);
  } else if (i < 131072 + 32768 + 8192 + 2048){
    int i4 = i - 131072 - 32768 - 8192;
    int r = i4 >> 6, k = i4 & 63;
    w4i[i4] = (r < 3) ? f2bf(W4[(size_t)k*3 + r]) : (unsigned short)0;
  }
  if (i < 768){
    float* w1c = (float*)(ws + OFF_W1C);
    w1c[i] = W1[(size_t)(512 + i/256)*256 + (i & 255)];
  }
  if (i == 0){
    int f = 1;
    for (int t = 1; t < 64; t += 2) if (ei32[t] != 0) { f = 0; break; }
    *(int*)(ws + OFF_FLAG) = f;
  }
}

// ---------------------------------------------------------------------------
// gemm1: PQ[n][o] = sum_k emb[n][k]*W1ab[k][o] (+ b1 for o<256).
// block = 256 (4 waves); block covers 32 nodes x 512 outs; wave: 128 outs.
// 2-deep emb prefetch, 1-deep (paired) W1 A-frag prefetch, no LDS, no barriers.
// ---------------------------------------------------------------------------
#define GSTEP(S, E0, E1, AA)                                                   \
  {                                                                            \
    const int k0g = (S)*16 + g2*8;                                             \
    f32x4 e0 = E0, e1 = E1;                                                    \
    bf16x8 a0 = AA##0, a1 = AA##1, a2 = AA##2, a3 = AA##3;                     \
    int kp = (S) + 2; if (kp > 15) kp = 15;                                    \
    {                                                                          \
      const float* ep = emb + (size_t)n0*256 + kp*16 + g2*8;                   \
      E0 = *(const f32x4*)(ep); E1 = *(const f32x4*)(ep + 4);                  \
      const int kpa = kp*16 + g2*8;                                            \
      AA##0 = *(const bf16x8*)(Wt + (size_t)(ob +  0 + ln)*256 + kpa);         \
      AA##1 = *(const bf16x8*)(Wt + (size_t)(ob + 32 + ln)*256 + kpa);         \
      AA##2 = *(const bf16x8*)(Wt + (size_t)(ob + 64 + ln)*256 + kpa);         \
      AA##3 = *(const bf16x8*)(Wt + (size_t)(ob + 96 + ln)*256 + kpa);         \
    }                                                                          \
    (void)k0g;                                                                 \
    unsigned bu0 = cvtpk(e0[0], e0[1]), bu1 = cvtpk(e0[2], e0[3]);             \
    unsigned bu2 = cvtpk(e1[0], e1[1]), bu3 = cvtpk(e1[2], e1[3]);             \
    u32x4 buv = {bu0, bu1, bu2, bu3};                                          \
    bf16x8 b = __builtin_bit_cast(bf16x8, buv);                                \
    acc0 = mfma32(a0, b, acc0);                                                \
    acc1 = mfma32(a1, b, acc1);                                                \
    acc2_ = mfma32(a2, b, acc2_);                                              \
    acc3_ = mfma32(a3, b, acc3_);                                              \
  }

__global__ __launch_bounds__(256, 3) void gemm1(const float* __restrict__ emb,
                                                const float* __restrict__ b1,
                                                char* __restrict__ ws)
{
  const int tid = threadIdx.x;
  const int wv = tid >> 6, l = tid & 63, ln = l & 31, g2 = l >> 5;
  const int nb = blockIdx.x * 32;
  const int ob = wv * 128;
  const unsigned short* Wt = (const unsigned short*)(ws + OFF_W1);
  unsigned short* PQ = (unsigned short*)(ws + OFF_PQ);

  int n = nb + ln;
  const int n0 = (n < NN) ? n : (NN - 1);

  f32x16 acc0 = zero16(), acc1 = zero16(), acc2_ = zero16(), acc3_ = zero16();

  // prime 2-deep emb, 2-buffer A-frags
  f32x4 eA0, eA1, eB0, eB1;
  bf16x8 aA0, aA1, aA2, aA3, aB0, aB1, aB2, aB3;
  {
    const float* ep = emb + (size_t)n0*256 + g2*8;
    eA0 = *(const f32x4*)(ep);        eA1 = *(const f32x4*)(ep + 4);
    eB0 = *(const f32x4*)(ep + 16);   eB1 = *(const f32x4*)(ep + 20);
    const int ka = g2*8, kb = 16 + g2*8;
    aA0 = *(const bf16x8*)(Wt + (size_t)(ob +  0 + ln)*256 + ka);
    aA1 = *(const bf16x8*)(Wt + (size_t)(ob + 32 + ln)*256 + ka);
    aA2 = *(const bf16x8*)(Wt + (size_t)(ob + 64 + ln)*256 + ka);
    aA3 = *(const bf16x8*)(Wt + (size_t)(ob + 96 + ln)*256 + ka);
    aB0 = *(const bf16x8*)(Wt + (size_t)(ob +  0 + ln)*256 + kb);
    aB1 = *(const bf16x8*)(Wt + (size_t)(ob + 32 + ln)*256 + kb);
    aB2 = *(const bf16x8*)(Wt + (size_t)(ob + 64 + ln)*256 + kb);
    aB3 = *(const bf16x8*)(Wt + (size_t)(ob + 96 + ln)*256 + kb);
  }

#pragma unroll 1
  for (int sb = 0; sb < 8; ++sb){
    GSTEP(2*sb,     eA0, eA1, aA);
    GSTEP(2*sb + 1, eB0, eB1, aB);
  }

  if (n < NN){
#pragma unroll
    for (int t = 0; t < 4; ++t){
      const f32x16& ac = (t==0)?acc0:(t==1)?acc1:(t==2)?acc2_:acc3_;
      const int obase = ob + t*32;
#pragma unroll
      for (int rr = 0; rr < 4; ++rr){
        int o = obase + rr*8 + g2*4;
        f32x4 bv = {0.f,0.f,0.f,0.f};
        if (obase < 256) bv = *(const f32x4*)(b1 + o);
        unsigned d0 = cvtpk(ac[rr*4+0]+bv[0], ac[rr*4+1]+bv[1]);
        unsigned d1 = cvtpk(ac[rr*4+2]+bv[2], ac[rr*4+3]+bv[3]);
        u32x2 st = {d0, d1};
        *(u32x2*)(PQ + (size_t)n*512 + o) = st;
      }
    }
  }
}

// ---------------------------------------------------------------------------
// fused: h1 = relu(P[src]+Q[dst]+attr@W1c) built in registers in B-frag layout;
// L2/L3/L4 MFMA with weights read from L2-hot global images (no LDS staging,
// no __syncthreads in body). 32 edges/wave, 128/block. hslot per-wave LDS.
// ---------------------------------------------------------------------------
#define L2STEP(S, PP, QQ)                                                      \
  {                                                                            \
    const int k0 = (S)*16 + g2*8;                                              \
    f32x4 w00 = *(const f32x4*)(w1c_lds +   0 + k0);                           \
    f32x4 w01 = *(const f32x4*)(w1c_lds +   4 + k0);                           \
    f32x4 w10 = *(const f32x4*)(w1c_lds + 256 + k0);                           \
    f32x4 w11 = *(const f32x4*)(w1c_lds + 260 + k0);                           \
    f32x4 w20 = *(const f32x4*)(w1c_lds + 512 + k0);                           \
    f32x4 w21 = *(const f32x4*)(w1c_lds + 516 + k0);                           \
    bf16x8 pc = PP, qc = QQ;                                                   \
    int kp = (S) + 2; if (kp > 15) kp = 15;                                    \
    PP = *(const bf16x8*)(PQ + (size_t)si*512 + kp*16 + g2*8);                 \
    QQ = *(const bf16x8*)(PQ + (size_t)di*512 + 256 + kp*16 + g2*8);           \
    u32x4 pu = __builtin_bit_cast(u32x4, pc);                                  \
    u32x4 qu = __builtin_bit_cast(u32x4, qc);                                  \
    f32x2 z2 = {0.f, 0.f};                                                     \
    unsigned bu[4];                                                            \
    _Pragma("unroll")                                                          \
    for (int d = 0; d < 4; ++d){                                               \
      f32x2 h = unpk(pu[d]) + unpk(qu[d]);                                     \
      f32x2 wc0 = (d<2) ? ((d==0)?(f32x2){w00[0],w00[1]}:(f32x2){w00[2],w00[3]}) \
                        : ((d==2)?(f32x2){w01[0],w01[1]}:(f32x2){w01[2],w01[3]});\
      f32x2 wc1 = (d<2) ? ((d==0)?(f32x2){w10[0],w10[1]}:(f32x2){w10[2],w10[3]}) \
                        : ((d==2)?(f32x2){w11[0],w11[1]}:(f32x2){w11[2],w11[3]});\
      f32x2 wc2 = (d<2) ? ((d==0)?(f32x2){w20[0],w20[1]}:(f32x2){w20[2],w20[3]}) \
                        : ((d==2)?(f32x2){w21[0],w21[1]}:(f32x2){w21[2],w21[3]});\
      h += wc0 * at0; h += wc1 * at1; h += wc2 * at2;                          \
      h = __builtin_elementwise_max(h, z2);                                    \
      bu[d] = cvtpk(h[0], h[1]);                                               \
    }                                                                          \
    u32x4 buv = {bu[0], bu[1], bu[2], bu[3]};                                  \
    bf16x8 b = __builtin_bit_cast(bf16x8, buv);                                \
    {                                                                          \
      bf16x8 af0 = *(const bf16x8*)(w2t + (size_t)(  0 + ln)*256 + k0);        \
      bf16x8 af1 = *(const bf16x8*)(w2t + (size_t)( 32 + ln)*256 + k0);        \
      bf16x8 af2 = *(const bf16x8*)(w2t + (size_t)( 64 + ln)*256 + k0);        \
      bf16x8 af3 = *(const bf16x8*)(w2t + (size_t)( 96 + ln)*256 + k0);        \
      acc20 = mfma32(af0, b, acc20);                                           \
      acc21 = mfma32(af1, b, acc21);                                           \
      acc22 = mfma32(af2, b, acc22);                                           \
      acc23 = mfma32(af3, b, acc23);                                           \
    }                                                                          \
  }

// Layer-3 pass, literal P (all reg indices static).
#define LAYER3_PASS(P, ACCA, ACCB)                                             \
  {                                                                            \
    _Pragma("unroll")                                                          \
    for (int th = 0; th < 2; ++th){                                            \
      _Pragma("unroll")                                                        \
      for (int rr = 0; rr < 4; ++rr){                                          \
        int fg = th*32 + rr*8 + g2*4;                                          \
        f32x4 bv = *(const f32x4*)(b2 + (2*(P)+th)*32 + rr*8 + g2*4);          \
        unsigned d0, d1;                                                       \
        if (th == 0){                                                          \
          d0 = cvtpk(ACCA[rr*4+0]+bv[0], ACCA[rr*4+1]+bv[1]);                  \
          d1 = cvtpk(ACCA[rr*4+2]+bv[2], ACCA[rr*4+3]+bv[3]);                  \
        } else {                                                               \
          d0 = cvtpk(ACCB[rr*4+0]+bv[0], ACCB[rr*4+1]+bv[1]);                  \
          d1 = cvtpk(ACCB[rr*4+2]+bv[2], ACCB[rr*4+3]+bv[3]);                  \
        }                                                                      \
        u32x2 st = {d0, d1};                                                   \
        *(u32x2*)(hslot + (size_t)ln*72 + fg) = st;                            \
      }                                                                        \
    }                                                                          \
    _Pragma("unroll")                                                          \
    for (int kq = 0; kq < 4; ++kq){                                            \
      bf16x8 bb = *(const bf16x8*)(hslot + (size_t)ln*72 + kq*16 + g2*8);      \
      bf16x8 af0 = *(const bf16x8*)(w3t + (size_t)(ln)*128      + (P)*64 + kq*16 + g2*8); \
      bf16x8 af1 = *(const bf16x8*)(w3t + (size_t)(32 + ln)*128 + (P)*64 + kq*16 + g2*8); \
      acc30 = mfma32(af0, bb, acc30);                                          \
      acc31 = mfma32(af1, bb, acc31);                                          \
    }                                                                          \
  }

__global__ __launch_bounds__(256, 3) void fused(const int* __restrict__ eidx,
                                                const float* __restrict__ attr,
                                                const float* __restrict__ b2,
                                                const float* __restrict__ b3,
                                                const float* __restrict__ b4,
                                                const char* __restrict__ ws,
                                                float* __restrict__ out)
{
  __shared__ __align__(16) float w1c_lds[768];
  __shared__ __align__(16) unsigned short hmem[4][2304];   // per-wave [32][72]

  const int tid = threadIdx.x;
  const int wv = tid >> 6, l = tid & 63, ln = l & 31, g2 = l >> 5;
  unsigned short* hslot = hmem[wv];

  const unsigned short* PQ  = (const unsigned short*)(ws + OFF_PQ);
  const unsigned short* w2t = (const unsigned short*)(ws + OFF_W2);
  const unsigned short* w3t = (const unsigned short*)(ws + OFF_W3);
  const unsigned short* w4t = (const unsigned short*)(ws + OFF_W4);
  const float* W1c = (const float*)(ws + OFF_W1C);
  const int flag64 = *(const int*)(ws + OFF_FLAG);

  if (tid < 192) ((f32x4*)w1c_lds)[tid] = ((const f32x4*)W1c)[tid];
  __syncthreads();

  const int eb = blockIdx.x * 128 + wv * 32;
  const int e = eb + ln;
  const bool ev = (e < NE);
  const int ec = ev ? e : 0;
  const int si = flag64 ? eidx[2*(size_t)ec]        : eidx[ec];
  const int di = flag64 ? eidx[2*((size_t)NE + ec)] : eidx[NE + ec];
  const float at0 = ev ? attr[(size_t)ec*3 + 0] : 0.f;
  const float at1 = ev ? attr[(size_t)ec*3 + 1] : 0.f;
  const float at2 = ev ? attr[(size_t)ec*3 + 2] : 0.f;

  // ---------------- Layer 2: h2 = relu(h1) @ W2, K=256 ---------------------
  f32x16 acc20 = zero16(), acc21 = zero16(), acc22 = zero16(), acc23 = zero16();

  bf16x8 pA, qA, pB, qB;
  pA = *(const bf16x8*)(PQ + (size_t)si*512 + g2*8);
  qA = *(const bf16x8*)(PQ + (size_t)di*512 + 256 + g2*8);
  pB = *(const bf16x8*)(PQ + (size_t)si*512 + 16 + g2*8);
  qB = *(const bf16x8*)(PQ + (size_t)di*512 + 256 + 16 + g2*8);

#pragma unroll 1
  for (int sb = 0; sb < 8; ++sb){
    L2STEP(2*sb,     pA, qA);
    L2STEP(2*sb + 1, pB, qB);
  }

  // ------------- Layer 3: h3 = relu(h2 @ W3 + b3), K=128, 2 passes ---------
  f32x16 acc30 = zero16(), acc31 = zero16();
  LAYER3_PASS(0, acc20, acc21);
  LAYER3_PASS(1, acc22, acc23);

  // h3 -> hslot (relu, +b3)
#pragma unroll
  for (int t = 0; t < 2; ++t){
#pragma unroll
    for (int rr = 0; rr < 4; ++rr){
      int fg = t*32 + rr*8 + g2*4;
      f32x4 bv = *(const f32x4*)(b3 + fg);
      unsigned d0, d1;
      if (t == 0){
        d0 = cvtpk(fmaxf(acc30[rr*4+0]+bv[0],0.f), fmaxf(acc30[rr*4+1]+bv[1],0.f));
        d1 = cvtpk(fmaxf(acc30[rr*4+2]+bv[2],0.f), fmaxf(acc30[rr*4+3]+bv[3],0.f));
      } else {
        d0 = cvtpk(fmaxf(acc31[rr*4+0]+bv[0],0.f), fmaxf(acc31[rr*4+1]+bv[1],0.f));
        d1 = cvtpk(fmaxf(acc31[rr*4+2]+bv[2],0.f), fmaxf(acc31[rr*4+3]+bv[3],0.f));
      }
      u32x2 st = {d0, d1};
      *(u32x2*)(hslot + (size_t)ln*72 + fg) = st;
    }
  }

  // ---------------- Layer 4: logits = h3 @ W4 + b4, K=64 -------------------
  f32x16 acc4 = zero16();
#pragma unroll
  for (int kq = 0; kq < 4; ++kq){
    bf16x8 af = *(const bf16x8*)(w4t + (size_t)ln*64 + kq*16 + g2*8);
    bf16x8 bb = *(const bf16x8*)(hslot + (size_t)ln*72 + kq*16 + g2*8);
    acc4 = mfma32(af, bb, acc4);
  }
  if (g2 == 0 && ev){
    out[(size_t)e*3 + 0] = acc4[0] + b4[0];
    out[(size_t)e*3 + 1] = acc4[1] + b4[1];
    out[(size_t)e*3 + 2] = acc4[2] + b4[2];
  }
}

// ---------------------------------------------------------------------------
extern "C" void kernel_launch(void* const* d_in, const int* in_sizes, int n_in,
                              void* d_out, int out_size, void* d_ws, size_t ws_size,
                              hipStream_t stream)
{
  const float* emb  = (const float*)d_in[0];
  const int*   eidx = (const int*)  d_in[1];
  const float* attr = (const float*)d_in[2];
  const float* W1   = (const float*)d_in[3];
  const float* b1   = (const float*)d_in[4];
  const float* W2   = (const float*)d_in[5];
  const float* b2   = (const float*)d_in[6];
  const float* W3   = (const float*)d_in[7];
  const float* b3   = (const float*)d_in[8];
  const float* W4   = (const float*)d_in[9];
  const float* b4   = (const float*)d_in[10];
  char* ws = (char*)d_ws;
  float* out = (float*)d_out;

  if (ws_size < WS_NEED) return;

  prep_pack<<<680, 256, 0, stream>>>(W1, W2, W3, W4, eidx, ws);
  gemm1<<<(NN + 31)/32, 256, 0, stream>>>(emb, b1, ws);
  fused<<<(NE + 127)/128, 256, 0, stream>>>(eidx, attr, b2, b3, b4, ws, out);
}

// Round 4
// 140.270 us; speedup vs baseline: 1.7779x; 1.7779x over previous
//
#include <hip/hip_runtime.h>
#include <hip/hip_bf16.h>
#include <stdint.h>
#include <stddef.h>

// ---------------------------------------------------------------------------
// InteractionPredictionHead: edge MLP.
// Rewrite: feats@W1 = P[src] + Q[dst] + attr@W1c + b1  (P,Q per-node).
// R4: attack TA line-request rate (R3 diagnosis: latency/request-bound).
//  - All weight images k-major [kq][g2][out][8] -> contiguous frag loads.
//  - fused: W2 staged ONCE in LDS (no K-loop barriers, contiguous ds_reads);
//    512thr/8 waves/block, 64 edges/wave; gathers remain per-lane (TA floor).
//  - gemm1: W1 slice register-stationary (128 VGPR/wave, loaded once,
//    coalesced); emb tile staged bf16 in LDS once per block (no 8x re-read).
// MFMA 32x32x16 bf16, swapped operands. Verified layouts (m74/m101):
//  A: row=lane&31, k=(lane>>5)*8+j ; B mirrored ; D: col=lane&31,
//  row=(r&3)+8*(r>>2)+4*(lane>>5).
// ---------------------------------------------------------------------------

#define NN 50000
#define NE 300000
#define KG(kq,g2) ((kq)*2+(g2))

using bf16x8 = __attribute__((ext_vector_type(8))) short;
using f32x16 = __attribute__((ext_vector_type(16))) float;
using f32x4  = __attribute__((ext_vector_type(4))) float;
using f32x2  = __attribute__((ext_vector_type(2))) float;
using u32x4  = __attribute__((ext_vector_type(4))) unsigned int;
using u32x2  = __attribute__((ext_vector_type(2))) unsigned int;

// ---- ws layout (bytes, 16B aligned) ----
#define OFF_PQ   0ULL
#define SZ_PQ    (50000ULL*512ULL*2ULL)          // PQ bf16 [n][512]
#define OFF_W1   (OFF_PQ + SZ_PQ)                // W1L bf16 [kq16*g2*2][512][8]
#define SZ_W1    (512ULL*256ULL*2ULL)
#define OFF_W1C  (OFF_W1 + SZ_W1)                // W1c f32 [3][256]
#define SZ_W1C   (3ULL*256ULL*4ULL)
#define OFF_W2   (OFF_W1C + SZ_W1C)              // W2L bf16 [kq16*2][128][8]
#define SZ_W2    (128ULL*256ULL*2ULL)
#define OFF_W3   (OFF_W2 + SZ_W2)                // W3L bf16 [kq8*2][64][8]
#define SZ_W3    (64ULL*128ULL*2ULL)
#define OFF_W4   (OFF_W3 + SZ_W3)                // W4L bf16 [kq4*2][32][8]
#define SZ_W4    (32ULL*64ULL*2ULL)
#define OFF_FLAG (OFF_W4 + SZ_W4)
#define WS_NEED  (OFF_FLAG + 16ULL)

__device__ __forceinline__ unsigned short f2bf(float x){
  unsigned u = __float_as_uint(x);
  unsigned r = 0x7FFFu + ((u >> 16) & 1u);
  return (unsigned short)((u + r) >> 16);
}
__device__ __forceinline__ unsigned cvtpk(float lo, float hi){
  unsigned r;
  asm("v_cvt_pk_bf16_f32 %0, %1, %2" : "=v"(r) : "v"(lo), "v"(hi));
  return r;
}
__device__ __forceinline__ f32x2 unpk(unsigned w){
  f32x2 r;
  r[0] = __uint_as_float(w << 16);
  r[1] = __uint_as_float(w & 0xFFFF0000u);
  return r;
}
__device__ __forceinline__ f32x16 mfma32(bf16x8 a, bf16x8 b, f32x16 c){
  return __builtin_amdgcn_mfma_f32_32x32x16_bf16(a, b, c, 0, 0, 0);
}
__device__ __forceinline__ f32x16 zero16(){
  f32x16 v;
#pragma unroll
  for (int i = 0; i < 16; ++i) v[i] = 0.f;
  return v;
}

// ---------------------------------------------------------------------------
// prep_pack: k-major weight images + int64 flag.
// threads = 131072 + 32768 + 8192 + 2048 = 174080 = 680*256
// ---------------------------------------------------------------------------
__global__ void prep_pack(const float* __restrict__ W1, const float* __restrict__ W2,
                          const float* __restrict__ W3, const float* __restrict__ W4,
                          const int* __restrict__ ei32, char* __restrict__ ws)
{
  int i = blockIdx.x * 256 + threadIdx.x;
  unsigned short* w1i = (unsigned short*)(ws + OFF_W1);
  unsigned short* w2i = (unsigned short*)(ws + OFF_W2);
  unsigned short* w3i = (unsigned short*)(ws + OFF_W3);
  unsigned short* w4i = (unsigned short*)(ws + OFF_W4);

  if (i < 131072){
    int j = i & 7, out = (i >> 3) & 511, kg = i >> 12;
    int k = (kg >> 1)*16 + (kg & 1)*8 + j;
    float v = (out < 256) ? W1[(size_t)k*256 + out]
                          : W1[(size_t)(256 + k)*256 + (out - 256)];
    w1i[i] = f2bf(v);
  } else if (i < 131072 + 32768){
    int i2 = i - 131072;
    int j = i2 & 7, out = (i2 >> 3) & 127, kg = i2 >> 10;
    int k = (kg >> 1)*16 + (kg & 1)*8 + j;
    w2i[i2] = f2bf(W2[(size_t)k*128 + out]);
  } else if (i < 131072 + 32768 + 8192){
    int i3 = i - 131072 - 32768;
    int j = i3 & 7, out = (i3 >> 3) & 63, kg = i3 >> 9;
    int k = (kg >> 1)*16 + (kg & 1)*8 + j;
    w3i[i3] = f2bf(W3[(size_t)k*64 + out]);
  } else if (i < 131072 + 32768 + 8192 + 2048){
    int i4 = i - 131072 - 32768 - 8192;
    int j = i4 & 7, out = (i4 >> 3) & 31, kg = i4 >> 8;
    int k = (kg >> 1)*16 + (kg & 1)*8 + j;
    w4i[i4] = (out < 3) ? f2bf(W4[(size_t)k*3 + out]) : (unsigned short)0;
  }
  if (i < 768){
    float* w1c = (float*)(ws + OFF_W1C);
    w1c[i] = W1[(size_t)(512 + i/256)*256 + (i & 255)];
  }
  if (i == 0){
    int f = 1;
    for (int t = 1; t < 64; t += 2) if (ei32[t] != 0) { f = 0; break; }
    *(int*)(ws + OFF_FLAG) = f;
  }
}

// ---------------------------------------------------------------------------
// gemm1: PQ[n][o] = sum_k emb[n][k]*W1ab[k][o] (+ b1 for o<256).
// block = 512 thr (8 waves), 64 nodes/block; wave w owns outs [w*64, w*64+64).
// W1 slice register-stationary (32x bf16x8 = 128 VGPR, coalesced load once).
// emb tile staged bf16 in LDS (k-major), read conflict-free contiguous.
// ---------------------------------------------------------------------------
__global__ __launch_bounds__(512, 2) void gemm1(const float* __restrict__ emb,
                                                const float* __restrict__ b1,
                                                char* __restrict__ ws)
{
  __shared__ __align__(16) unsigned short embL[32*64*8];  // 32KB [kg][node][8]

  const int tid = threadIdx.x;
  const int wv = tid >> 6, l = tid & 63, ln = l & 31, g2 = l >> 5;
  const int nb = blockIdx.x * 64;
  const int ob2 = wv * 64;
  const unsigned short* w1L = (const unsigned short*)(ws + OFF_W1);
  unsigned short* PQ = (unsigned short*)(ws + OFF_PQ);

  // ---- weight preload: 2 tiles x 16 kq, coalesced (contiguous 16B/lane) ----
  bf16x8 aw[2][16];
#pragma unroll
  for (int kq = 0; kq < 16; ++kq){
#pragma unroll
    for (int t2 = 0; t2 < 2; ++t2){
      aw[t2][kq] = *(const bf16x8*)(w1L + ((size_t)KG(kq,g2)*512 + ob2 + t2*32 + ln)*8);
    }
  }

  // ---- stage emb tile -> LDS bf16 k-major ----
#pragma unroll
  for (int it = 0; it < 8; ++it){
    int u = it*512 + tid;                      // 0..4095, 4 f32 each
    int kg = u >> 7, node = (u >> 1) & 63, half = u & 1;
    int n = nb + node; if (n >= NN) n = NN - 1;
    int k = (kg >> 1)*16 + (kg & 1)*8 + half*4;
    f32x4 e = *(const f32x4*)(emb + (size_t)n*256 + k);
    u32x2 w; w[0] = cvtpk(e[0], e[1]); w[1] = cvtpk(e[2], e[3]);
    *(u32x2*)(embL + (size_t)kg*512 + node*8 + half*4) = w;
  }
  __syncthreads();

  // ---- K loop: pure ds_read + MFMA ----
  f32x16 acc[2][2];
  acc[0][0] = zero16(); acc[0][1] = zero16();
  acc[1][0] = zero16(); acc[1][1] = zero16();
#pragma unroll
  for (int kq = 0; kq < 16; ++kq){
    bf16x8 b0 = *(const bf16x8*)(embL + ((size_t)KG(kq,g2)*64 +      ln)*8);
    bf16x8 b1v = *(const bf16x8*)(embL + ((size_t)KG(kq,g2)*64 + 32 + ln)*8);
    acc[0][0] = mfma32(aw[0][kq], b0,  acc[0][0]);
    acc[1][0] = mfma32(aw[1][kq], b0,  acc[1][0]);
    acc[0][1] = mfma32(aw[0][kq], b1v, acc[0][1]);
    acc[1][1] = mfma32(aw[1][kq], b1v, acc[1][1]);
  }

  // ---- epilogue: +b1 (P half), bf16, store ----
#pragma unroll
  for (int t2 = 0; t2 < 2; ++t2){
#pragma unroll
    for (int bg = 0; bg < 2; ++bg){
      int n = nb + bg*32 + ln;
      if (n < NN){
#pragma unroll
        for (int rr = 0; rr < 4; ++rr){
          int o = ob2 + t2*32 + rr*8 + g2*4;
          f32x4 bv = {0.f,0.f,0.f,0.f};
          if (ob2 < 256) bv = *(const f32x4*)(b1 + o);
          unsigned d0 = cvtpk(acc[t2][bg][rr*4+0]+bv[0], acc[t2][bg][rr*4+1]+bv[1]);
          unsigned d1 = cvtpk(acc[t2][bg][rr*4+2]+bv[2], acc[t2][bg][rr*4+3]+bv[3]);
          u32x2 st = {d0, d1};
          *(u32x2*)(PQ + (size_t)n*512 + o) = st;
        }
      }
    }
  }
}

// ---------------------------------------------------------------------------
// fused: 512 thr (8 waves), 64 edges/wave. W2+W1c in LDS once; no K-loop
// barriers. h1 built in registers in B-frag layout; W3/W4 from L2 (k-major).
// ---------------------------------------------------------------------------

// static pair select from two f32x4 (D = 0..3)
#define PAIRX(LO, HI, D) ((D)==0 ? (f32x2){(LO)[0],(LO)[1]} : \
                          (D)==1 ? (f32x2){(LO)[2],(LO)[3]} : \
                          (D)==2 ? (f32x2){(HI)[0],(HI)[1]} : \
                                   (f32x2){(HI)[2],(HI)[3]})

#define H1BUILD(PC, QC, A0, A1, A2, BOUT)                                      \
  {                                                                            \
    u32x4 pu = __builtin_bit_cast(u32x4, PC);                                  \
    u32x4 qu = __builtin_bit_cast(u32x4, QC);                                  \
    f32x2 z2 = {0.f, 0.f};                                                     \
    unsigned bu0, bu1, bu2, bu3;                                               \
    _Pragma("unroll")                                                          \
    for (int d = 0; d < 4; ++d){                                               \
      f32x2 h = unpk(pu[d]) + unpk(qu[d]);                                     \
      h += PAIRX(w0lo, w0hi, d) * (A0);                                        \
      h += PAIRX(w1lo, w1hi, d) * (A1);                                        \
      h += PAIRX(w2lo, w2hi, d) * (A2);                                        \
      h = __builtin_elementwise_max(h, z2);                                    \
      unsigned c = cvtpk(h[0], h[1]);                                          \
      if (d==0) bu0 = c; else if (d==1) bu1 = c; else if (d==2) bu2 = c;       \
      else bu3 = c;                                                            \
    }                                                                          \
    u32x4 buv = {bu0, bu1, bu2, bu3};                                          \
    BOUT = __builtin_bit_cast(bf16x8, buv);                                    \
  }

#define L2STEP(S, X)                                                           \
  {                                                                            \
    const int kq_ = (S);                                                       \
    const int k0 = kq_*16 + g2*8;                                              \
    bf16x8 pc0 = p##X##0, qc0 = q##X##0, pc1 = p##X##1, qc1 = q##X##1;         \
    int kp = (S) + 2; if (kp > 15) kp = 15;                                    \
    p##X##0 = *(const bf16x8*)(PQ + (size_t)si0*512 + kp*16 + g2*8);           \
    q##X##0 = *(const bf16x8*)(PQ + (size_t)di0*512 + 256 + kp*16 + g2*8);     \
    p##X##1 = *(const bf16x8*)(PQ + (size_t)si1*512 + kp*16 + g2*8);           \
    q##X##1 = *(const bf16x8*)(PQ + (size_t)di1*512 + 256 + kp*16 + g2*8);     \
    f32x4 w0lo = *(const f32x4*)(w1c_lds +   0 + k0);                          \
    f32x4 w0hi = *(const f32x4*)(w1c_lds +   4 + k0);                          \
    f32x4 w1lo = *(const f32x4*)(w1c_lds + 256 + k0);                          \
    f32x4 w1hi = *(const f32x4*)(w1c_lds + 260 + k0);                          \
    f32x4 w2lo = *(const f32x4*)(w1c_lds + 512 + k0);                          \
    f32x4 w2hi = *(const f32x4*)(w1c_lds + 516 + k0);                          \
    bf16x8 b0, b1;                                                             \
    H1BUILD(pc0, qc0, a0e0, a1e0, a2e0, b0);                                   \
    H1BUILD(pc1, qc1, a0e1, a1e1, a2e1, b1);                                   \
    _Pragma("unroll")                                                          \
    for (int t = 0; t < 4; ++t){                                               \
      bf16x8 af = *(const bf16x8*)(w2L_lds + ((size_t)KG(kq_,g2)*128 + t*32 + ln)*8); \
      acc2[t][0] = mfma32(af, b0, acc2[t][0]);                                 \
      acc2[t][1] = mfma32(af, b1, acc2[t][1]);                                 \
    }                                                                          \
  }

// Layer-3 pass with literal P (acc indices static).
#define LAYER3_PASS(P)                                                         \
  {                                                                            \
    _Pragma("unroll")                                                          \
    for (int th = 0; th < 2; ++th){                                            \
      _Pragma("unroll")                                                        \
      for (int bg = 0; bg < 2; ++bg){                                          \
        _Pragma("unroll")                                                      \
        for (int rr = 0; rr < 4; ++rr){                                        \
          int fg = th*32 + rr*8 + g2*4;                                        \
          f32x4 bv = *(const f32x4*)(b2 + (2*(P)+th)*32 + rr*8 + g2*4);        \
          unsigned d0, d1;                                                     \
          if (th == 0){                                                        \
            d0 = cvtpk(acc2[2*(P)][bg][rr*4+0]+bv[0], acc2[2*(P)][bg][rr*4+1]+bv[1]); \
            d1 = cvtpk(acc2[2*(P)][bg][rr*4+2]+bv[2], acc2[2*(P)][bg][rr*4+3]+bv[3]); \
          } else {                                                             \
            d0 = cvtpk(acc2[2*(P)+1][bg][rr*4+0]+bv[0], acc2[2*(P)+1][bg][rr*4+1]+bv[1]); \
            d1 = cvtpk(acc2[2*(P)+1][bg][rr*4+2]+bv[2], acc2[2*(P)+1][bg][rr*4+3]+bv[3]); \
          }                                                                    \
          u32x2 st = {d0, d1};                                                 \
          *(u32x2*)(hslot + (size_t)(bg*32 + ln)*72 + fg) = st;                \
        }                                                                      \
      }                                                                        \
    }                                                                          \
    _Pragma("unroll")                                                          \
    for (int kq = 0; kq < 4; ++kq){                                            \
      bf16x8 bb0 = *(const bf16x8*)(hslot + (size_t)(     ln)*72 + kq*16 + g2*8); \
      bf16x8 bb1 = *(const bf16x8*)(hslot + (size_t)(32 + ln)*72 + kq*16 + g2*8); \
      _Pragma("unroll")                                                        \
      for (int t2 = 0; t2 < 2; ++t2){                                          \
        bf16x8 af = *(const bf16x8*)(w3L + ((size_t)KG(4*(P)+kq,g2)*64 + t2*32 + ln)*8); \
        acc3[t2][0] = mfma32(af, bb0, acc3[t2][0]);                            \
        acc3[t2][1] = mfma32(af, bb1, acc3[t2][1]);                            \
      }                                                                        \
    }                                                                          \
  }

__global__ __launch_bounds__(512, 2) void fused(const int* __restrict__ eidx,
                                                const float* __restrict__ attr,
                                                const float* __restrict__ b2,
                                                const float* __restrict__ b3,
                                                const float* __restrict__ b4,
                                                const char* __restrict__ ws,
                                                float* __restrict__ out)
{
  __shared__ __align__(16) unsigned short w2L_lds[32768];   // 64KB [kg][128][8]
  __shared__ __align__(16) float w1c_lds[768];              // 3KB
  __shared__ __align__(16) unsigned short hmem[8*4608];     // 72KB, per-wave [64][72]

  const int tid = threadIdx.x;
  const int wv = tid >> 6, l = tid & 63, ln = l & 31, g2 = l >> 5;
  unsigned short* hslot = hmem + wv*4608;

  const unsigned short* PQ  = (const unsigned short*)(ws + OFF_PQ);
  const unsigned short* w3L = (const unsigned short*)(ws + OFF_W3);
  const unsigned short* w4L = (const unsigned short*)(ws + OFF_W4);
  const float* W1c = (const float*)(ws + OFF_W1C);
  const int flag64 = *(const int*)(ws + OFF_FLAG);

  // stage W2 (linear copy, image already k-major) + W1c
  {
    const uint4* src = (const uint4*)(ws + OFF_W2);
    uint4* dst = (uint4*)w2L_lds;
#pragma unroll
    for (int it = 0; it < 8; ++it) dst[it*512 + tid] = src[it*512 + tid];
    if (tid < 192) ((f32x4*)w1c_lds)[tid] = ((const f32x4*)W1c)[tid];
  }
  __syncthreads();

  const int eb = blockIdx.x * 512 + wv * 64;
  int e0 = eb + ln, e1 = eb + 32 + ln;
  bool ev0 = (e0 < NE), ev1 = (e1 < NE);
  int ec0 = ev0 ? e0 : 0, ec1 = ev1 ? e1 : 0;
  const int si0 = flag64 ? eidx[2*(size_t)ec0]        : eidx[ec0];
  const int di0 = flag64 ? eidx[2*((size_t)NE + ec0)] : eidx[NE + ec0];
  const int si1 = flag64 ? eidx[2*(size_t)ec1]        : eidx[ec1];
  const int di1 = flag64 ? eidx[2*((size_t)NE + ec1)] : eidx[NE + ec1];
  const float a0e0 = ev0 ? attr[(size_t)ec0*3 + 0] : 0.f;
  const float a1e0 = ev0 ? attr[(size_t)ec0*3 + 1] : 0.f;
  const float a2e0 = ev0 ? attr[(size_t)ec0*3 + 2] : 0.f;
  const float a0e1 = ev1 ? attr[(size_t)ec1*3 + 0] : 0.f;
  const float a1e1 = ev1 ? attr[(size_t)ec1*3 + 1] : 0.f;
  const float a2e1 = ev1 ? attr[(size_t)ec1*3 + 2] : 0.f;

  // ---------------- Layer 2: K=256, 64 edges/wave, no barriers -------------
  f32x16 acc2[4][2];
#pragma unroll
  for (int t = 0; t < 4; ++t){ acc2[t][0] = zero16(); acc2[t][1] = zero16(); }

  bf16x8 pA0, qA0, pA1, qA1, pB0, qB0, pB1, qB1;
  pA0 = *(const bf16x8*)(PQ + (size_t)si0*512 + g2*8);
  qA0 = *(const bf16x8*)(PQ + (size_t)di0*512 + 256 + g2*8);
  pA1 = *(const bf16x8*)(PQ + (size_t)si1*512 + g2*8);
  qA1 = *(const bf16x8*)(PQ + (size_t)di1*512 + 256 + g2*8);
  pB0 = *(const bf16x8*)(PQ + (size_t)si0*512 + 16 + g2*8);
  qB0 = *(const bf16x8*)(PQ + (size_t)di0*512 + 256 + 16 + g2*8);
  pB1 = *(const bf16x8*)(PQ + (size_t)si1*512 + 16 + g2*8);
  qB1 = *(const bf16x8*)(PQ + (size_t)di1*512 + 256 + 16 + g2*8);

#pragma unroll 1
  for (int sb = 0; sb < 8; ++sb){
    L2STEP(2*sb,     A);
    L2STEP(2*sb + 1, B);
  }

  // ------------- Layer 3: K=128, 2 passes ----------------------------------
  f32x16 acc3[2][2];
  acc3[0][0] = zero16(); acc3[0][1] = zero16();
  acc3[1][0] = zero16(); acc3[1][1] = zero16();
  LAYER3_PASS(0);
  LAYER3_PASS(1);

  // h3 -> hslot (relu, +b3)
#pragma unroll
  for (int t2 = 0; t2 < 2; ++t2){
#pragma unroll
    for (int bg = 0; bg < 2; ++bg){
#pragma unroll
      for (int rr = 0; rr < 4; ++rr){
        int fg = t2*32 + rr*8 + g2*4;
        f32x4 bv = *(const f32x4*)(b3 + fg);
        unsigned d0, d1;
        if (t2 == 0){
          d0 = cvtpk(fmaxf(acc3[0][bg][rr*4+0]+bv[0],0.f), fmaxf(acc3[0][bg][rr*4+1]+bv[1],0.f));
          d1 = cvtpk(fmaxf(acc3[0][bg][rr*4+2]+bv[2],0.f), fmaxf(acc3[0][bg][rr*4+3]+bv[3],0.f));
        } else {
          d0 = cvtpk(fmaxf(acc3[1][bg][rr*4+0]+bv[0],0.f), fmaxf(acc3[1][bg][rr*4+1]+bv[1],0.f));
          d1 = cvtpk(fmaxf(acc3[1][bg][rr*4+2]+bv[2],0.f), fmaxf(acc3[1][bg][rr*4+3]+bv[3],0.f));
        }
        u32x2 st = {d0, d1};
        *(u32x2*)(hslot + (size_t)(bg*32 + ln)*72 + fg) = st;
      }
    }
  }

  // ---------------- Layer 4: K=64 ------------------------------------------
  f32x16 acc40 = zero16(), acc41 = zero16();
#pragma unroll
  for (int kq = 0; kq < 4; ++kq){
    bf16x8 af = *(const bf16x8*)(w4L + ((size_t)KG(kq,g2)*32 + ln)*8);
    bf16x8 bb0 = *(const bf16x8*)(hslot + (size_t)(     ln)*72 + kq*16 + g2*8);
    bf16x8 bb1 = *(const bf16x8*)(hslot + (size_t)(32 + ln)*72 + kq*16 + g2*8);
    acc40 = mfma32(af, bb0, acc40);
    acc41 = mfma32(af, bb1, acc41);
  }
  if (g2 == 0){
    float c0 = b4[0], c1 = b4[1], c2 = b4[2];
    if (ev0){
      out[(size_t)e0*3 + 0] = acc40[0] + c0;
      out[(size_t)e0*3 + 1] = acc40[1] + c1;
      out[(size_t)e0*3 + 2] = acc40[2] + c2;
    }
    if (ev1){
      out[(size_t)e1*3 + 0] = acc41[0] + c0;
      out[(size_t)e1*3 + 1] = acc41[1] + c1;
      out[(size_t)e1*3 + 2] = acc41[2] + c2;
    }
  }
}

// ---------------------------------------------------------------------------
extern "C" void kernel_launch(void* const* d_in, const int* in_sizes, int n_in,
                              void* d_out, int out_size, void* d_ws, size_t ws_size,
                              hipStream_t stream)
{
  const float* emb  = (const float*)d_in[0];
  const int*   eidx = (const int*)  d_in[1];
  const float* attr = (const float*)d_in[2];
  const float* W1   = (const float*)d_in[3];
  const float* b1   = (const float*)d_in[4];
  const float* W2   = (const float*)d_in[5];
  const float* b2   = (const float*)d_in[6];
  const float* W3   = (const float*)d_in[7];
  const float* b3   = (const float*)d_in[8];
  const float* W4   = (const float*)d_in[9];
  const float* b4   = (const float*)d_in[10];
  char* ws = (char*)d_ws;
  float* out = (float*)d_out;

  if (ws_size < WS_NEED) return;

  prep_pack<<<680, 256, 0, stream>>>(W1, W2, W3, W4, eidx, ws);
  gemm1<<<(NN + 63)/64, 512, 0, stream>>>(emb, b1, ws);
  fused<<<(NE + 511)/512, 512, 0, stream>>>(eidx, attr, b2, b3, b4, ws, out);
}

// Round 5
// 117.366 us; speedup vs baseline: 2.1248x; 1.1951x over previous
//
#include <hip/hip_runtime.h>
#include <hip/hip_bf16.h>
#include <stdint.h>
#include <stddef.h>

// ---------------------------------------------------------------------------
// InteractionPredictionHead: edge MLP.
// feats@W1 = P[src] + Q[dst] + attr@W1c + b1  (P,Q per-node, 50k not 300k).
// R5: layers 2-4 use mfma_f32_16x16x32_bf16 (16 edges/wave):
//  - acc2 = 32 regs -> <=128 regs/wave -> 16 waves/CU (2 blocks of 512 thr)
//  - an edge's 4 lanes read ONE contiguous 64B line per 32-k step (TA halved)
//  - W2 in LDS; W3/W4 + per-wave h-slots aliased into W2's LDS after K-loop
// gemm1: out-half blocks, 32 outs/wave reg-stationary -> <=128 regs, 2 blk/CU.
// Layouts (m89/m91 verified D for 16x16x32): D col=lane&15, row=(lane>>4)*4+r;
// A/B: lane&15 = row/col, k = (lane>>4)*8 + j. 32x32 (gemm1) as before.
// ---------------------------------------------------------------------------

#define NN 50000
#define NE 300000
#define KG(kq,g2) ((kq)*2+(g2))

using bf16x8 = __attribute__((ext_vector_type(8))) short;
using f32x16 = __attribute__((ext_vector_type(16))) float;
using f32x4  = __attribute__((ext_vector_type(4))) float;
using f32x2  = __attribute__((ext_vector_type(2))) float;
using u32x4  = __attribute__((ext_vector_type(4))) unsigned int;
using u32x2  = __attribute__((ext_vector_type(2))) unsigned int;

// ---- ws layout (bytes, 16B aligned) ----
#define OFF_PQ   0ULL
#define SZ_PQ    (50000ULL*512ULL*2ULL)          // PQ bf16 [n][512]
#define OFF_W1   (OFF_PQ + SZ_PQ)                // W1 img (32-style) [kg32][512][8]
#define SZ_W1    (512ULL*256ULL*2ULL)
#define OFF_W1C  (OFF_W1 + SZ_W1)                // W1c f32 [3][256]
#define SZ_W1C   (3ULL*256ULL*4ULL)
#define OFF_W2   (OFF_W1C + SZ_W1C)              // W2 img (16-style) [sg32][128][8]
#define SZ_W2    (128ULL*256ULL*2ULL)
#define OFF_W3   (OFF_W2 + SZ_W2)                // W3 img (16-style) [sg16][64][8]
#define SZ_W3    (64ULL*128ULL*2ULL)
#define OFF_W4   (OFF_W3 + SZ_W3)                // W4 img (16-style) [sg8][16][8]
#define SZ_W4    (16ULL*64ULL*2ULL)
#define OFF_FLAG (OFF_W4 + SZ_W4)
#define WS_NEED  (OFF_FLAG + 16ULL)

__device__ __forceinline__ unsigned short f2bf(float x){
  unsigned u = __float_as_uint(x);
  unsigned r = 0x7FFFu + ((u >> 16) & 1u);
  return (unsigned short)((u + r) >> 16);
}
__device__ __forceinline__ unsigned cvtpk(float lo, float hi){
  unsigned r;
  asm("v_cvt_pk_bf16_f32 %0, %1, %2" : "=v"(r) : "v"(lo), "v"(hi));
  return r;
}
__device__ __forceinline__ f32x2 unpk(unsigned w){
  f32x2 r;
  r[0] = __uint_as_float(w << 16);
  r[1] = __uint_as_float(w & 0xFFFF0000u);
  return r;
}
__device__ __forceinline__ f32x16 mfma32(bf16x8 a, bf16x8 b, f32x16 c){
  return __builtin_amdgcn_mfma_f32_32x32x16_bf16(a, b, c, 0, 0, 0);
}
__device__ __forceinline__ f32x4 mfma16(bf16x8 a, bf16x8 b, f32x4 c){
  return __builtin_amdgcn_mfma_f32_16x16x32_bf16(a, b, c, 0, 0, 0);
}
__device__ __forceinline__ f32x16 zero16(){
  f32x16 v;
#pragma unroll
  for (int i = 0; i < 16; ++i) v[i] = 0.f;
  return v;
}

// ---------------------------------------------------------------------------
// prep_pack: weight images + int64 flag.
// threads = 131072 (W1) + 32768 (W2) + 8192 (W3) + 1024 (W4) = 173056 = 676*256
// ---------------------------------------------------------------------------
__global__ void prep_pack(const float* __restrict__ W1, const float* __restrict__ W2,
                          const float* __restrict__ W3, const float* __restrict__ W4,
                          const int* __restrict__ ei32, char* __restrict__ ws)
{
  int i = blockIdx.x * 256 + threadIdx.x;
  unsigned short* w1i = (unsigned short*)(ws + OFF_W1);
  unsigned short* w2i = (unsigned short*)(ws + OFF_W2);
  unsigned short* w3i = (unsigned short*)(ws + OFF_W3);
  unsigned short* w4i = (unsigned short*)(ws + OFF_W4);

  if (i < 131072){
    // 32-style: idx = (kg*512 + out)*8 + j ; k = (kg>>1)*16 + (kg&1)*8 + j
    int j = i & 7, out = (i >> 3) & 511, kg = i >> 12;
    int k = (kg >> 1)*16 + (kg & 1)*8 + j;
    float v = (out < 256) ? W1[(size_t)k*256 + out]
                          : W1[(size_t)(256 + k)*256 + (out - 256)];
    w1i[i] = f2bf(v);
  } else if (i < 131072 + 32768){
    // 16-style: idx = (sg*128 + out)*8 + j ; k = (sg>>2)*32 + (sg&3)*8 + j
    int i2 = i - 131072;
    int j = i2 & 7, out = (i2 >> 3) & 127, sg = i2 >> 10;
    int k = (sg >> 2)*32 + (sg & 3)*8 + j;
    w2i[i2] = f2bf(W2[(size_t)k*128 + out]);
  } else if (i < 131072 + 32768 + 8192){
    int i3 = i - 131072 - 32768;
    int j = i3 & 7, out = (i3 >> 3) & 63, sg = i3 >> 9;
    int k = (sg >> 2)*32 + (sg & 3)*8 + j;
    w3i[i3] = f2bf(W3[(size_t)k*64 + out]);
  } else if (i < 131072 + 32768 + 8192 + 1024){
    int i4 = i - 131072 - 32768 - 8192;
    int j = i4 & 7, out = (i4 >> 3) & 15, sg = i4 >> 7;
    int k = (sg >> 2)*32 + (sg & 3)*8 + j;
    w4i[i4] = (out < 3) ? f2bf(W4[(size_t)k*3 + out]) : (unsigned short)0;
  }
  if (i < 768){
    float* w1c = (float*)(ws + OFF_W1C);
    w1c[i] = W1[(size_t)(512 + i/256)*256 + (i & 255)];
  }
  if (i == 0){
    int f = 1;
    for (int t = 1; t < 64; t += 2) if (ei32[t] != 0) { f = 0; break; }
    *(int*)(ws + OFF_FLAG) = f;
  }
}

// ---------------------------------------------------------------------------
// gemm1: PQ = emb @ W1ab (+b1). Out-half blocks: grid = 782 nodegrps x 2.
// 512 thr, 8 waves x 32 outs (reg-stationary aw[16] = 64 VGPR), 64 nodes.
// launch_bounds(512,4) -> <=128 regs -> 2 blocks/CU.
// ---------------------------------------------------------------------------
__global__ __launch_bounds__(512, 4) void gemm1(const float* __restrict__ emb,
                                                const float* __restrict__ b1,
                                                char* __restrict__ ws)
{
  __shared__ __align__(16) unsigned short embL[32*64*8];  // 32KB [kg][node][8]

  const int tid = threadIdx.x;
  const int wv = tid >> 6, l = tid & 63, ln = l & 31, g2 = l >> 5;
  const int bid = blockIdx.x;
  const int nb = (bid >> 1) * 64;
  const int oh = bid & 1;
  const int ob = oh*256 + wv*32;
  const unsigned short* w1L = (const unsigned short*)(ws + OFF_W1);
  unsigned short* PQ = (unsigned short*)(ws + OFF_PQ);

  // weight preload: 16 frags (64 VGPR), contiguous 16B/lane
  bf16x8 aw[16];
#pragma unroll
  for (int kq = 0; kq < 16; ++kq)
    aw[kq] = *(const bf16x8*)(w1L + ((size_t)KG(kq,g2)*512 + ob + ln)*8);

  // stage emb tile -> LDS bf16 k-major
#pragma unroll
  for (int it = 0; it < 8; ++it){
    int u = it*512 + tid;                      // 0..4095
    int kg = u >> 7, node = (u >> 1) & 63, half = u & 1;
    int n = nb + node; if (n >= NN) n = NN - 1;
    int k = (kg >> 1)*16 + (kg & 1)*8 + half*4;
    f32x4 e = *(const f32x4*)(emb + (size_t)n*256 + k);
    u32x2 w; w[0] = cvtpk(e[0], e[1]); w[1] = cvtpk(e[2], e[3]);
    *(u32x2*)(embL + (size_t)kg*512 + node*8 + half*4) = w;
  }
  __syncthreads();

  f32x16 acc0 = zero16(), acc1 = zero16();
#pragma unroll
  for (int kq = 0; kq < 16; ++kq){
    bf16x8 b0  = *(const bf16x8*)(embL + ((size_t)KG(kq,g2)*64 +      ln)*8);
    bf16x8 b1v = *(const bf16x8*)(embL + ((size_t)KG(kq,g2)*64 + 32 + ln)*8);
    acc0 = mfma32(aw[kq], b0,  acc0);
    acc1 = mfma32(aw[kq], b1v, acc1);
  }

#pragma unroll
  for (int bg = 0; bg < 2; ++bg){
    int n = nb + bg*32 + ln;
    if (n < NN){
#pragma unroll
      for (int rr = 0; rr < 4; ++rr){
        int o = ob + rr*8 + g2*4;
        f32x4 bv = {0.f,0.f,0.f,0.f};
        if (oh == 0) bv = *(const f32x4*)(b1 + o);
        unsigned d0, d1;
        if (bg == 0){
          d0 = cvtpk(acc0[rr*4+0]+bv[0], acc0[rr*4+1]+bv[1]);
          d1 = cvtpk(acc0[rr*4+2]+bv[2], acc0[rr*4+3]+bv[3]);
        } else {
          d0 = cvtpk(acc1[rr*4+0]+bv[0], acc1[rr*4+1]+bv[1]);
          d1 = cvtpk(acc1[rr*4+2]+bv[2], acc1[rr*4+3]+bv[3]);
        }
        u32x2 st = {d0, d1};
        *(u32x2*)(PQ + (size_t)n*512 + o) = st;
      }
    }
  }
}

// ---------------------------------------------------------------------------
// fused: 512 thr (8 waves), 16 edges/wave, 16x16x32 MFMA.
// LDS: [0,65536) = W2 image, then (after bar) hslots (8x4352) + W3/W4 images;
//      [65536,68608) = w1c.  3 barriers total.
// ---------------------------------------------------------------------------

#define PAIRX(LO, HI, D) ((D)==0 ? (f32x2){(LO)[0],(LO)[1]} : \
                          (D)==1 ? (f32x2){(LO)[2],(LO)[3]} : \
                          (D)==2 ? (f32x2){(HI)[0],(HI)[1]} : \
                                   (f32x2){(HI)[2],(HI)[3]})

// One K=32 step of layer 2: build h1 B-frag in regs, 8 MFMA tiles from LDS.
#define L2STEP(S, X)                                                           \
  {                                                                            \
    const int ks_ = (S);                                                       \
    bf16x8 pc = p##X, qc = q##X;                                               \
    int kp = ks_ + 2; if (kp > 7) kp = 7;                                      \
    p##X = *(const bf16x8*)(PQ + (size_t)si*512 + kp*32 + g4*8);               \
    q##X = *(const bf16x8*)(PQ + (size_t)di*512 + 256 + kp*32 + g4*8);         \
    const int kb = ks_*32 + g4*8;                                              \
    f32x4 w0lo = *(const f32x4*)(w1c_lds +   0 + kb);                          \
    f32x4 w0hi = *(const f32x4*)(w1c_lds +   4 + kb);                          \
    f32x4 w1lo = *(const f32x4*)(w1c_lds + 256 + kb);                          \
    f32x4 w1hi = *(const f32x4*)(w1c_lds + 260 + kb);                          \
    f32x4 w2lo = *(const f32x4*)(w1c_lds + 512 + kb);                          \
    f32x4 w2hi = *(const f32x4*)(w1c_lds + 516 + kb);                          \
    u32x4 pu = __builtin_bit_cast(u32x4, pc);                                  \
    u32x4 qu = __builtin_bit_cast(u32x4, qc);                                  \
    f32x2 z2 = {0.f, 0.f};                                                     \
    unsigned bu0, bu1, bu2, bu3;                                               \
    _Pragma("unroll")                                                          \
    for (int d = 0; d < 4; ++d){                                               \
      f32x2 h = unpk(pu[d]) + unpk(qu[d]);                                     \
      h += PAIRX(w0lo, w0hi, d) * at0;                                         \
      h += PAIRX(w1lo, w1hi, d) * at1;                                         \
      h += PAIRX(w2lo, w2hi, d) * at2;                                         \
      h = __builtin_elementwise_max(h, z2);                                    \
      unsigned c = cvtpk(h[0], h[1]);                                          \
      if (d==0) bu0 = c; else if (d==1) bu1 = c; else if (d==2) bu2 = c;       \
      else bu3 = c;                                                            \
    }                                                                          \
    u32x4 buv = {bu0, bu1, bu2, bu3};                                          \
    bf16x8 b = __builtin_bit_cast(bf16x8, buv);                                \
    const char* abase = smem + (size_t)(ks_*4 + g4)*2048 + c16*16;             \
    _Pragma("unroll")                                                          \
    for (int t = 0; t < 8; ++t){                                               \
      bf16x8 af = *(const bf16x8*)(abase + t*256);                             \
      acc2[t] = mfma16(af, b, acc2[t]);                                        \
    }                                                                          \
  }

__global__ __launch_bounds__(512, 4) void fused(const int* __restrict__ eidx,
                                                const float* __restrict__ attr,
                                                const float* __restrict__ b2,
                                                const float* __restrict__ b3,
                                                const float* __restrict__ b4,
                                                const char* __restrict__ ws,
                                                float* __restrict__ out)
{
  __shared__ __align__(16) char smem[68608];
  const int tid = threadIdx.x;
  const int wv = tid >> 6, l = tid & 63, c16 = l & 15, g4 = l >> 4;

  const unsigned short* PQ = (const unsigned short*)(ws + OFF_PQ);
  const float* W1c = (const float*)(ws + OFF_W1C);
  const int flag64 = *(const int*)(ws + OFF_FLAG);
  const float* w1c_lds = (const float*)(smem + 65536);

  // stage W2 (64KB, linear) + w1c (3KB)
  {
    const uint4* src = (const uint4*)(ws + OFF_W2);
    uint4* dst = (uint4*)smem;
#pragma unroll
    for (int it = 0; it < 8; ++it) dst[it*512 + tid] = src[it*512 + tid];
    if (tid < 192) ((f32x4*)(smem + 65536))[tid] = ((const f32x4*)W1c)[tid];
  }
  __syncthreads();

  const int eb = blockIdx.x * 128 + wv * 16;
  const int e = eb + c16;
  const bool ev = (e < NE);
  const int ec = ev ? e : 0;
  const int si = flag64 ? eidx[2*(size_t)ec]        : eidx[ec];
  const int di = flag64 ? eidx[2*((size_t)NE + ec)] : eidx[NE + ec];
  const float at0 = ev ? attr[(size_t)ec*3 + 0] : 0.f;
  const float at1 = ev ? attr[(size_t)ec*3 + 1] : 0.f;
  const float at2 = ev ? attr[(size_t)ec*3 + 2] : 0.f;

  // ---------------- Layer 2: K=256 (8 x 32k-steps), 128 outs ---------------
  f32x4 acc2[8];
#pragma unroll
  for (int t = 0; t < 8; ++t) acc2[t] = (f32x4){0.f,0.f,0.f,0.f};

  bf16x8 pA, qA, pB, qB;
  pA = *(const bf16x8*)(PQ + (size_t)si*512 + g4*8);
  qA = *(const bf16x8*)(PQ + (size_t)di*512 + 256 + g4*8);
  pB = *(const bf16x8*)(PQ + (size_t)si*512 + 32 + g4*8);
  qB = *(const bf16x8*)(PQ + (size_t)di*512 + 256 + 32 + g4*8);

#pragma unroll 1
  for (int sb = 0; sb < 4; ++sb){
    L2STEP(2*sb,     A);
    L2STEP(2*sb + 1, B);
  }

  __syncthreads();   // everyone done reading W2 region

  // stage W3+W4 (contiguous in ws: 16384+2048 = 18432B) into dead W2 space
  {
    const uint4* s3 = (const uint4*)(ws + OFF_W3);
    uint4* d3 = (uint4*)(smem + 36864);
    for (int i = tid; i < 1152; i += 512) d3[i] = s3[i];
  }

  // write h2 -> per-wave hslot [16 edges][136] bf16 (stride 272B: 16B-aligned,
  // 2-way banks max)
  unsigned short* hslot = (unsigned short*)(smem + wv*4352);
#pragma unroll
  for (int t = 0; t < 8; ++t){
    f32x4 bv = *(const f32x4*)(b2 + t*16 + g4*4);
    unsigned d0 = cvtpk(acc2[t][0]+bv[0], acc2[t][1]+bv[1]);
    unsigned d1 = cvtpk(acc2[t][2]+bv[2], acc2[t][3]+bv[3]);
    u32x2 st = {d0, d1};
    *(u32x2*)(hslot + (size_t)c16*136 + t*16 + g4*4) = st;
  }
  __syncthreads();   // W3/W4 visible

  // ---------------- Layer 3: K=128 (4 steps), 64 outs ----------------------
  f32x4 acc3[4];
#pragma unroll
  for (int t = 0; t < 4; ++t) acc3[t] = (f32x4){0.f,0.f,0.f,0.f};
  const char* w3b = smem + 36864;
#pragma unroll
  for (int ks = 0; ks < 4; ++ks){
    bf16x8 bb = *(const bf16x8*)(hslot + (size_t)c16*136 + ks*32 + g4*8);
    const char* ab = w3b + (size_t)(ks*4 + g4)*1024 + c16*16;
#pragma unroll
    for (int t = 0; t < 4; ++t){
      bf16x8 af = *(const bf16x8*)(ab + t*256);
      acc3[t] = mfma16(af, bb, acc3[t]);
    }
  }

  // h3 -> hslot (relu, +b3); same-wave RAW on LDS is in-order
#pragma unroll
  for (int t = 0; t < 4; ++t){
    f32x4 bv = *(const f32x4*)(b3 + t*16 + g4*4);
    unsigned d0 = cvtpk(fmaxf(acc3[t][0]+bv[0],0.f), fmaxf(acc3[t][1]+bv[1],0.f));
    unsigned d1 = cvtpk(fmaxf(acc3[t][2]+bv[2],0.f), fmaxf(acc3[t][3]+bv[3],0.f));
    u32x2 st = {d0, d1};
    *(u32x2*)(hslot + (size_t)c16*136 + t*16 + g4*4) = st;
  }

  // ---------------- Layer 4: K=64 (2 steps), 3 outs ------------------------
  f32x4 acc4 = {0.f,0.f,0.f,0.f};
  const char* w4b = smem + 53248;
#pragma unroll
  for (int ks = 0; ks < 2; ++ks){
    bf16x8 bb = *(const bf16x8*)(hslot + (size_t)c16*136 + ks*32 + g4*8);
    bf16x8 af = *(const bf16x8*)(w4b + (size_t)(ks*4 + g4)*256 + c16*16);
    acc4 = mfma16(af, bb, acc4);
  }
  if (g4 == 0 && ev){
    out[(size_t)e*3 + 0] = acc4[0] + b4[0];
    out[(size_t)e*3 + 1] = acc4[1] + b4[1];
    out[(size_t)e*3 + 2] = acc4[2] + b4[2];
  }
}

// ---------------------------------------------------------------------------
extern "C" void kernel_launch(void* const* d_in, const int* in_sizes, int n_in,
                              void* d_out, int out_size, void* d_ws, size_t ws_size,
                              hipStream_t stream)
{
  const float* emb  = (const float*)d_in[0];
  const int*   eidx = (const int*)  d_in[1];
  const float* attr = (const float*)d_in[2];
  const float* W1   = (const float*)d_in[3];
  const float* b1   = (const float*)d_in[4];
  const float* W2   = (const float*)d_in[5];
  const float* b2   = (const float*)d_in[6];
  const float* W3   = (const float*)d_in[7];
  const float* b3   = (const float*)d_in[8];
  const float* W4   = (const float*)d_in[9];
  const float* b4   = (const float*)d_in[10];
  char* ws = (char*)d_ws;
  float* out = (float*)d_out;

  if (ws_size < WS_NEED) return;

  prep_pack<<<676, 256, 0, stream>>>(W1, W2, W3, W4, eidx, ws);
  gemm1<<<((NN + 63)/64)*2, 512, 0, stream>>>(emb, b1, ws);
  fused<<<(NE + 127)/128, 512, 0, stream>>>(eidx, attr, b2, b3, b4, ws, out);
}